// Round 3
// baseline (182.783 us; speedup 1.0000x reference)
//
#include <hip/hip_runtime.h>

// VectorQuantizer: latents (16,128,64,64) f32, codebook (1024,128) f32.
// out[b,d,h,w] = codebook[argmin_k fl(fl(x2 - 2*dot(x,e_k)) + e2_k)][d]
//
// MFMA bf16 scoring + exact fp32 rescue:
//  phase 1: 16x16x32 bf16 MFMA scores (fp32 acc) -> per-px min in the
//           x2-free domain s' = fl(e2_k - 2*C_k)  (translation by x2 does
//           not change the argmin; its fp32-composition rounding ~2ulp(x2)
//           ~3e-5 is folded into the additive slop below).
//  phase 2: recompute s'; candidates = { k : s' <= min' + 2*M[px] },
//           M = 2e-4*sqrt(x2) + 2.5e-4   (Cauchy-Schwarz bf16-dot bound
//           + fp32 slop, inflated from the validated 1.5e-4 to absorb the
//           domain shift).
//  rescue:  exact fp32 serial ascending-d fmaf chain (UNCHANGED numerics:
//           same values, same order -- x read from global now) on ~2
//           cands/px; lex (t3,k) u64 atomicMin keeps np first-index
//           tie-break.
//
// Round-6 (occupancy round -- unified VGPR+AGPR file was capping us at
// ~2 waves/SIMD; shrink every footprint):
//  - x tile in LDS is now bf16, TRANSPOSED [px][d] with XOR slot-swizzle
//    (slot ^= px&15 per 16B slot): A-build = 16 x ds_read_b128 conflict-free
//    (was 128 scalar 4-way-conflicted reads + 128 f2bf per thread, 4x
//    redundant across waves). f2bf runs once per element at staging.
//    LDS 40 -> 23.8 KB.
//  - x2 and rescue read fp32 x from GLOBAL (L2/L3-resident, coalesced
//    within the 256B px-tile): identical values, identical chain order.
//  - score epilogue is 1 fma (s' = fmaf(-2,C,e2c)); x2r[16] regs gone.
//  - prep: e2 rows staged through LDS transpose (coalesced global reads,
//    identical serial chains) -- was 32 lanes x 128 stride-512B loads,
//    ~60us of the inter-kernel gap.
//  - NO launch_bounds floor (round-1 lesson: forcing occupancy spills).

typedef __attribute__((ext_vector_type(8))) short short8;
typedef __attribute__((ext_vector_type(4))) float f32x4;

#define VQ_D 128
#define VQ_K 1024
#define VQ_HW 4096
#define CAND_CAP 1728

__device__ inline unsigned short f2bf(float f) {   // RNE fp32->bf16
    unsigned u = __float_as_uint(f);
    return (unsigned short)((u + 0x7FFFu + ((u >> 16) & 1u)) >> 16);
}

__global__ __launch_bounds__(256)
void vq_prep_kernel(const float* __restrict__ cb, unsigned short* __restrict__ cbbf,
                    float* __restrict__ e2) {
    __shared__ __align__(16) float rows[32][132];    // +4 pad: 4-way on chain reads
    const int tid = threadIdx.x;
    const int k0  = blockIdx.x << 5;                 // 32 codes/block, grid=32
    const float4* s4 = (const float4*)(cb + (size_t)k0 * VQ_D);
    ushort4* d4 = (ushort4*)(cbbf + (size_t)k0 * VQ_D);
    #pragma unroll
    for (int i = 0; i < 4; ++i) {                    // 1024 float4 per block
        const int idx = i * 256 + tid;               // coalesced
        const float4 v = s4[idx];
        const int r  = idx >> 5;                     // row within 32-row tile
        const int c4 = (idx & 31) << 2;
        *(float4*)(&rows[r][c4]) = v;                // 528B row pitch: 16B-aligned
        ushort4 p;
        p.x = f2bf(v.x); p.y = f2bf(v.y); p.z = f2bf(v.z); p.w = f2bf(v.w);
        d4[idx] = p;
    }
    __syncthreads();
    if (tid < 32) {                                  // serial chain, same order
        float s = 0.f;
        #pragma unroll
        for (int d = 0; d < VQ_D; ++d) {
            const float v = rows[tid][d];
            s = fmaf(v, v, s);
        }
        e2[k0 + tid] = s;
    }
}

__global__ __launch_bounds__(256)
void vq_main_kernel(const float* __restrict__ latents,
                    const float* __restrict__ cb,
                    const unsigned short* __restrict__ cbbf,
                    const float* __restrict__ e2,
                    float* __restrict__ out) {
    // bf16 x tile, [px][d], 256B/row, 16B slots XOR-swizzled by px&15.
    __shared__ __align__(16) unsigned short xbf[64 * 128];   // 16 KB
    __shared__ float x2s[64];
    __shared__ float threshs[64];
    __shared__ unsigned long long fkey[64];
    __shared__ __align__(16) unsigned int cand[CAND_CAP];    // 6.75 KB
    __shared__ int ncand;
    // bfminw lives in cand's storage: last read is before the barrier that
    // precedes the first cand write (disjoint lifetimes).
    float (*bfminw)[64] = (float (*)[64])cand;

    const int tid  = threadIdx.x;
    const int lane = tid & 63;
    const int wave = __builtin_amdgcn_readfirstlane(tid >> 6);
    const int quad = lane >> 4;
    const int mm   = lane & 15;
    const int blk  = blockIdx.x;
    const int b    = blk >> 6;
    const int hw0  = (blk & 63) << 6;

    const float* xg = latents + (size_t)b * VQ_D * VQ_HW + hw0;

    // ---- stage x tile: coalesced float4 loads, f2bf once, swizzled b32 writes
    {
        const int px4 = (tid & 15) << 2;
        const int db  = (tid >> 4) << 3;
        #pragma unroll
        for (int dp = 0; dp < 4; ++dp) {             // d-pairs
            const int d0 = db + dp * 2;
            const float4 va = *(const float4*)(xg + (size_t)d0 * VQ_HW + px4);
            const float4 vb = *(const float4*)(xg + (size_t)(d0 + 1) * VQ_HW + px4);
            const float* fa = (const float*)&va;
            const float* fb = (const float*)&vb;
            #pragma unroll
            for (int i = 0; i < 4; ++i) {
                const int px = px4 + i;
                const unsigned lo = f2bf(fa[i]);
                const unsigned hi = f2bf(fb[i]);
                const int slot = (d0 >> 3) ^ (px & 15);
                *(unsigned*)((char*)xbf + px * 256 + slot * 16 + (d0 & 7) * 2) =
                    lo | (hi << 16);
            }
        }
    }
    if (tid == 0) ncand = 0;
    if (tid < 64) fkey[tid] = ~0ULL;

    // x2 per px: serial ascending-d chain from GLOBAL (identical values/order)
    if (tid < 64) {
        float s = 0.f;
        #pragma unroll
        for (int d = 0; d < VQ_D; ++d) {
            const float v = xg[(size_t)d * VQ_HW + tid];
            s = fmaf(v, v, s);
        }
        x2s[tid] = s;
    }
    __syncthreads();   // xbf + x2s ready

    // ---- A fragments (64 VGPR, held all sweep): px=p*16+mm, d=t*32+quad*8+j
    //      xbf slot-swizzle makes each b128 read conflict-free.
    short8 A[16];
    #pragma unroll
    for (int p = 0; p < 4; ++p) {
        const int px = p * 16 + mm;
        #pragma unroll
        for (int t = 0; t < 4; ++t) {
            const int slot = (t * 4 + quad) ^ mm;    // px&15 == mm
            A[p * 4 + t] = *(const short8*)((const char*)xbf + px * 256 + slot * 16);
        }
    }

    const float* e2g = e2 + wave * 256 + mm;   // e2 for code group c: e2g[c*16]

    // B-frag base: code = wave*256 + c*16 + mm, d = t*32 + quad*8 + j
    const unsigned short* bbase = cbbf + (size_t)(wave * 256 + mm) * VQ_D + quad * 8;

    // ---- phase 1: x2-free score min per px:  s' = e2_k - 2*dot_bf ----
    float bmin[16];
    #pragma unroll
    for (int i = 0; i < 16; ++i) bmin[i] = 1e30f;

    #pragma unroll 1
    for (int c = 0; c < 16; ++c) {
        short8 B[4];
        #pragma unroll
        for (int t = 0; t < 4; ++t)
            B[t] = *(const short8*)(bbase + (size_t)c * 16 * VQ_D + t * 32);
        const float e2c = e2g[c * 16];
        f32x4 C[4] = {{0.f,0.f,0.f,0.f},{0.f,0.f,0.f,0.f},
                      {0.f,0.f,0.f,0.f},{0.f,0.f,0.f,0.f}};
        #pragma unroll
        for (int t = 0; t < 4; ++t)
            #pragma unroll
            for (int p = 0; p < 4; ++p)
                C[p] = __builtin_amdgcn_mfma_f32_16x16x32_bf16(
                           A[p * 4 + t], B[t], C[p], 0, 0, 0);
        #pragma unroll
        for (int p = 0; p < 4; ++p)
            #pragma unroll
            for (int r = 0; r < 4; ++r) {
                const float s = fmaf(-2.0f, C[p][r], e2c);
                bmin[p * 4 + r] = fminf(bmin[p * 4 + r], s);
            }
    }

    // reduce min across the 16 lanes of each quad-group (code dimension)
    #pragma unroll
    for (int i = 0; i < 16; ++i) {
        float v = bmin[i];
        v = fminf(v, __shfl_xor(v, 1));
        v = fminf(v, __shfl_xor(v, 2));
        v = fminf(v, __shfl_xor(v, 4));
        v = fminf(v, __shfl_xor(v, 8));
        bmin[i] = v;
    }
    if (mm == 0) {
        #pragma unroll
        for (int p = 0; p < 4; ++p)
            #pragma unroll
            for (int r = 0; r < 4; ++r)
                bfminw[wave][p * 16 + quad * 4 + r] = bmin[p * 4 + r];
    }
    __syncthreads();
    if (tid < 64) {
        const float mn = fminf(fminf(bfminw[0][tid], bfminw[1][tid]),
                               fminf(bfminw[2][tid], bfminw[3][tid]));
        const float M = 2.0e-4f * sqrtf(x2s[tid]) + 2.5e-4f;   // +1e-4 domain slop
        threshs[tid] = mn + 2.0f * M;
    }
    __syncthreads();   // after this barrier bfminw is dead; cand may be written

    float thr[16];
    #pragma unroll
    for (int p = 0; p < 4; ++p)
        #pragma unroll
        for (int r = 0; r < 4; ++r)
            thr[p * 4 + r] = threshs[p * 16 + quad * 4 + r];

    // ---- phase 2: recompute s', collect candidates ----
    #pragma unroll 1
    for (int c = 0; c < 16; ++c) {
        short8 B[4];
        #pragma unroll
        for (int t = 0; t < 4; ++t)
            B[t] = *(const short8*)(bbase + (size_t)c * 16 * VQ_D + t * 32);
        const float e2c = e2g[c * 16];
        f32x4 C[4] = {{0.f,0.f,0.f,0.f},{0.f,0.f,0.f,0.f},
                      {0.f,0.f,0.f,0.f},{0.f,0.f,0.f,0.f}};
        #pragma unroll
        for (int t = 0; t < 4; ++t)
            #pragma unroll
            for (int p = 0; p < 4; ++p)
                C[p] = __builtin_amdgcn_mfma_f32_16x16x32_bf16(
                           A[p * 4 + t], B[t], C[p], 0, 0, 0);
        #pragma unroll
        for (int p = 0; p < 4; ++p)
            #pragma unroll
            for (int r = 0; r < 4; ++r) {
                const float s = fmaf(-2.0f, C[p][r], e2c);
                if (s <= thr[p * 4 + r]) {
                    const int idx = atomicAdd(&ncand, 1);
                    if (idx < CAND_CAP) {
                        const int px   = p * 16 + quad * 4 + r;
                        const int code = wave * 256 + c * 16 + mm;
                        cand[idx] = ((unsigned)px << 16) | (unsigned)code;
                    }
                }
            }
    }
    __syncthreads();

    // ---- rescue: exact fp32 serial chain on candidates, one per lane.
    //      x read from GLOBAL (same values/order as prior LDS path).
    const int nc = ncand < CAND_CAP ? ncand : CAND_CAP;
    for (int i = tid; i < nc; i += 256) {
        const unsigned pc = cand[i];
        const int px = (int)(pc >> 16);
        const int k  = (int)(pc & 0xFFFFu);
        const float* crow = cb + (size_t)k * VQ_D;
        float dot = 0.f;
        #pragma unroll
        for (int q = 0; q < 32; ++q) {
            const float4 cv = *(const float4*)(crow + q * 4);
            dot = fmaf(xg[(size_t)(q * 4 + 0) * VQ_HW + px], cv.x, dot);
            dot = fmaf(xg[(size_t)(q * 4 + 1) * VQ_HW + px], cv.y, dot);
            dot = fmaf(xg[(size_t)(q * 4 + 2) * VQ_HW + px], cv.z, dot);
            dot = fmaf(xg[(size_t)(q * 4 + 3) * VQ_HW + px], cv.w, dot);
        }
        const float t3 = (x2s[px] - 2.0f * dot) + e2[k];
        const unsigned long long key =
            ((unsigned long long)__float_as_uint(t3) << 32) | (unsigned)k;
        atomicMin(&fkey[px], key);
    }
    __syncthreads();

    // ---- writeback: vectorized codebook reads, nontemporal out stores ----
    {
        const int px = tid & 63;
        const int dh = tid >> 6;
        const int fb = (int)(fkey[px] & 0xFFFFFFFFULL);
        const float* crow = cb + (size_t)fb * VQ_D + dh * 32;
        float* og = out + (size_t)b * VQ_D * VQ_HW + hw0;
        #pragma unroll
        for (int j = 0; j < 8; ++j) {
            const float4 cv = *(const float4*)(crow + j * 4);
            const int d = dh * 32 + j * 4;
            __builtin_nontemporal_store(cv.x, &og[(size_t)(d + 0) * VQ_HW + px]);
            __builtin_nontemporal_store(cv.y, &og[(size_t)(d + 1) * VQ_HW + px]);
            __builtin_nontemporal_store(cv.z, &og[(size_t)(d + 2) * VQ_HW + px]);
            __builtin_nontemporal_store(cv.w, &og[(size_t)(d + 3) * VQ_HW + px]);
        }
    }
}

extern "C" void kernel_launch(void* const* d_in, const int* in_sizes, int n_in,
                              void* d_out, int out_size, void* d_ws, size_t ws_size,
                              hipStream_t stream) {
    const float* latents = (const float*)d_in[0];
    const float* cb      = (const float*)d_in[1];
    unsigned short* cbbf = (unsigned short*)d_ws;              // 256 KB
    float* e2            = (float*)((char*)d_ws + 262144);     // 4 KB
    float* out           = (float*)d_out;

    vq_prep_kernel<<<dim3(32), dim3(256), 0, stream>>>(cb, cbbf, e2);
    vq_main_kernel<<<dim3(1024), dim3(256), 0, stream>>>(latents, cb, cbbf, e2, out);
}